// Round 1
// baseline (390.177 us; speedup 1.0000x reference)
//
#include <hip/hip_runtime.h>

// SelfAttentionCNN reduced form:
//   M = X^T X (64x64), ST = Wg^T M Wf (8x8), Beta = rowsoftmax(ST),
//   u = Beta^T Wv, w = Gamma * Wh u (64), V_p = w . x_p,
//   out.flat[k] = x.flat[k] + V[k mod P]  with P = 2^19 power of two:
//   out[p][c] = x[p][c] + V[(p & 8191)*64 + c]

#define P_PIX (32 * 128 * 128)   // 524288 = 2^19
#define C_CH 64
#define NGROUP 8192              // P_PIX / 64

// ---------------- K1: M = X^T X ----------------
// 1024 blocks x 256 threads. Tile = 128 pixels staged in LDS (32 KB).
// Each thread owns a 4x4 tile of M; one atomicAdd per entry per block at end.
__global__ __launch_bounds__(256) void k_cov(const float* __restrict__ x,
                                             float* __restrict__ M) {
    __shared__ float lds[128 * 64];
    const int t = threadIdx.x;
    const int i0 = (t >> 4) << 2;   // 0..60
    const int j0 = (t & 15) << 2;   // 0..60
    float acc[4][4] = {};

    const int ntiles = P_PIX / 128;   // 4096
    for (int tile = blockIdx.x; tile < ntiles; tile += gridDim.x) {
        const float4* src = (const float4*)(x + (size_t)tile * 128 * 64);
        __syncthreads();   // previous iteration's readers done
        #pragma unroll
        for (int l = 0; l < 8; ++l) {
            ((float4*)lds)[t + 256 * l] = src[t + 256 * l];
        }
        __syncthreads();
        #pragma unroll 4
        for (int pix = 0; pix < 128; ++pix) {
            float av[4], bv[4];
            *(float4*)av = *(const float4*)&lds[pix * 64 + i0];
            *(float4*)bv = *(const float4*)&lds[pix * 64 + j0];
            #pragma unroll
            for (int a = 0; a < 4; ++a)
                #pragma unroll
                for (int b = 0; b < 4; ++b)
                    acc[a][b] = fmaf(av[a], bv[b], acc[a][b]);
        }
    }
    #pragma unroll
    for (int a = 0; a < 4; ++a)
        #pragma unroll
        for (int b = 0; b < 4; ++b)
            atomicAdd(&M[(i0 + a) * 64 + (j0 + b)], acc[a][b]);
}

// ---------------- K2: Beta, w ----------------
// Single wave. ST entries are O(1e4): max-subtract before exp.
__global__ __launch_bounds__(64) void k_beta(const float* __restrict__ M,
                                             const float* __restrict__ Wf,
                                             const float* __restrict__ Wg,
                                             const float* __restrict__ Wh,
                                             const float* __restrict__ Wv,
                                             const float* __restrict__ Gamma,
                                             float* __restrict__ w_out) {
    __shared__ float Tl[64][8];
    __shared__ float STl[64];
    __shared__ float El[64];
    __shared__ float Bl[64];
    __shared__ float ul[8];
    const int t = threadIdx.x;   // 0..63

    // T = M @ Wf  (row t)
    float Tr[8] = {};
    for (int b = 0; b < 64; ++b) {
        float m = M[t * 64 + b];
        #pragma unroll
        for (int j = 0; j < 8; ++j) Tr[j] = fmaf(m, Wf[b * 8 + j], Tr[j]);
    }
    #pragma unroll
    for (int j = 0; j < 8; ++j) Tl[t][j] = Tr[j];
    __syncthreads();

    // ST[i][j] = sum_a Wg[a][i] * T[a][j]   (i = t>>3, j = t&7)
    const int i = t >> 3, j = t & 7;
    float st = 0.f;
    for (int a = 0; a < 64; ++a) st = fmaf(Wg[a * 8 + i], Tl[a][j], st);
    STl[t] = st;
    __syncthreads();

    float mx = STl[i * 8];
    #pragma unroll
    for (int jj = 1; jj < 8; ++jj) mx = fmaxf(mx, STl[i * 8 + jj]);
    float e = expf(st - mx);
    El[t] = e;
    __syncthreads();

    float den = 0.f;
    #pragma unroll
    for (int jj = 0; jj < 8; ++jj) den += El[i * 8 + jj];
    Bl[t] = e / den;
    __syncthreads();

    if (t < 8) {  // u[j] = sum_i Beta[i][j] * Wv[i]
        float u = 0.f;
        #pragma unroll
        for (int ii = 0; ii < 8; ++ii) u += Bl[ii * 8 + t] * Wv[ii];
        ul[t] = u;
    }
    __syncthreads();

    // w[c] = Gamma * sum_j Wh[c][j] * u[j]
    float wv = 0.f;
    #pragma unroll
    for (int jj = 0; jj < 8; ++jj) wv = fmaf(Wh[t * 8 + jj], ul[jj], wv);
    w_out[t] = wv * Gamma[0];
}

// ---------------- K3: fused V + output ----------------
// Group r (0..8191): V-chunk vbuf[c] = w . x_row(r*64+c), then the 64 output
// rows p = r + 8192*s get out[p][c] = x[p][c] + vbuf[c].
// Thread map: s = t>>2 (row 0..63), q = t&3 (16-channel quarter).
__global__ __launch_bounds__(256) void k_out(const float* __restrict__ x,
                                             const float* __restrict__ wvec,
                                             float* __restrict__ out) {
    __shared__ float wl[64];
    __shared__ float vbuf[64];
    const int t = threadIdx.x;
    if (t < 64) wl[t] = wvec[t];
    const int s = t >> 2;
    const int q = t & 3;

    for (int r = blockIdx.x; r < NGROUP; r += gridDim.x) {
        __syncthreads();   // wl ready (first iter) / prev vbuf readers done
        // ---- V phase: pixel r*64+s, channels q*16..q*16+15
        const float* src = x + ((size_t)(r * 64 + s) * 64 + q * 16);
        float part = 0.f;
        #pragma unroll
        for (int jj = 0; jj < 4; ++jj) {
            float4 v = *(const float4*)(src + jj * 4);
            const float* wp = &wl[q * 16 + jj * 4];
            part += v.x * wp[0] + v.y * wp[1] + v.z * wp[2] + v.w * wp[3];
        }
        part += __shfl_xor(part, 1);
        part += __shfl_xor(part, 2);
        if (q == 0) vbuf[s] = part;
        __syncthreads();
        // ---- out phase: row p = r + 8192*s
        const size_t base = (size_t)(r + 8192 * s) * 64 + q * 16;
        const float4* xin = (const float4*)(x + base);
        float4* o = (float4*)(out + base);
        #pragma unroll
        for (int jj = 0; jj < 4; ++jj) {
            float4 v = xin[jj];
            const float* vp = &vbuf[q * 16 + jj * 4];
            o[jj] = make_float4(v.x + vp[0], v.y + vp[1], v.z + vp[2], v.w + vp[3]);
        }
    }
}

extern "C" void kernel_launch(void* const* d_in, const int* in_sizes, int n_in,
                              void* d_out, int out_size, void* d_ws, size_t ws_size,
                              hipStream_t stream) {
    const float* x     = (const float*)d_in[0];
    const float* Wf    = (const float*)d_in[1];
    const float* Wg    = (const float*)d_in[2];
    const float* Wh    = (const float*)d_in[3];
    const float* Wv    = (const float*)d_in[4];
    const float* Gamma = (const float*)d_in[5];
    float* out = (float*)d_out;

    float* M = (float*)d_ws;          // 4096 floats
    float* w = M + 4096;              // 64 floats

    hipMemsetAsync(M, 0, 4096 * sizeof(float), stream);
    hipLaunchKernelGGL(k_cov, dim3(1024), dim3(256), 0, stream, x, M);
    hipLaunchKernelGGL(k_beta, dim3(1), dim3(64), 0, stream, M, Wf, Wg, Wh, Wv, Gamma, w);
    hipLaunchKernelGGL(k_out, dim3(2048), dim3(256), 0, stream, x, w, out);
}

// Round 2
// 296.758 us; speedup vs baseline: 1.3148x; 1.3148x over previous
//
#include <hip/hip_runtime.h>

// SelfAttentionCNN reduced form:
//   M = X^T X (64x64), ST = Wg^T M Wf (8x8), Beta = rowsoftmax(ST),
//   u = Beta^T Wv, w = Gamma * Wh u (64), V_p = w . x_p,
//   out.flat[k] = x.flat[k] + V[k & (2^19-1)]

#define P_PIX (32 * 128 * 128)   // 524288 = 2^19
#define NGROUP 8192              // P_PIX / 64
#define NTILE 4096               // P_PIX / 128 (128-pixel tiles)
#define COV_BLOCKS 512

typedef __attribute__((ext_vector_type(8))) short bf16x8;
typedef __attribute__((ext_vector_type(4))) float f32x4;

__device__ __forceinline__ unsigned f2bf_bits(float f) {
    unsigned u = __builtin_bit_cast(unsigned, f);
    return (u + 0x7FFFu + ((u >> 16) & 1u)) >> 16;   // RNE to bf16 bits
}
__device__ __forceinline__ float bfbits2f(unsigned hb) {
    return __builtin_bit_cast(float, hb << 16);
}

// ---------------- K1: M = X^T X via MFMA (bf16 hi/lo split) ----------------
// 512 blocks x 256 threads. Tile = 128 pixels staged TRANSPOSED in LDS as
// bf16 hi + lo, XOR-swizzled (chan-pitch 256B would be a 16-way bank
// conflict on ds_read_b128 otherwise). Each wave owns a 32x32 quadrant of M
// (2x2 MFMA tiles); M = Hh^T Hh + Hh^T Hl + Hl^T Hh. Registers accumulate
// across all 8 tiles; one atomicAdd per entry per block at the end.
__global__ __launch_bounds__(256) void k_cov(const float* __restrict__ x,
                                             float* __restrict__ M) {
    __shared__ char lds[65536];      // xh: [64][256B], xl: [64][256B]
    char* const xh = lds;
    char* const xl = lds + 32768;
    const int t = threadIdx.x;
    const int w = t >> 6;            // wave 0..3
    const int l = t & 63;
    const int i2 = t & 63;           // pixel pair (2 pixels)
    const int cg = t >> 6;           // 16-chan group for staging
    const int wi = (w >> 1) * 32;    // M row-block base
    const int wj = (w & 1) * 32;     // M col-block base

    f32x4 acc[2][2] = {};

    for (int tile = blockIdx.x; tile < NTILE; tile += COV_BLOCKS) {
        const float* src = x + (size_t)tile * 128 * 64;
        __syncthreads();             // prev MFMA readers done
        // ---- stage: pixels 2*i2, 2*i2+1, chans cg*16..+15, hi/lo split ----
        #pragma unroll
        for (int f = 0; f < 4; ++f) {
            const int c0 = cg * 16 + f * 4;
            float4 va = *(const float4*)(src + (2 * i2) * 64 + c0);
            float4 vb = *(const float4*)(src + (2 * i2 + 1) * 64 + c0);
            const float* pa = (const float*)&va;
            const float* pb = (const float*)&vb;
            #pragma unroll
            for (int e = 0; e < 4; ++e) {
                const int c = c0 + e;
                unsigned ha = f2bf_bits(pa[e]);
                unsigned hb = f2bf_bits(pb[e]);
                unsigned la = f2bf_bits(pa[e] - bfbits2f(ha));
                unsigned lb = f2bf_bits(pb[e] - bfbits2f(hb));
                const int off = c * 256 + ((4 * i2) ^ ((c & 7) << 4));
                *(unsigned*)(xh + off) = ha | (hb << 16);
                *(unsigned*)(xl + off) = la | (lb << 16);
            }
        }
        __syncthreads();
        // ---- MFMA: 4 K-steps of 32 pixels ----
        #pragma unroll
        for (int ks = 0; ks < 4; ++ks) {
            auto frag = [&](const char* base, int cbase) -> bf16x8 {
                const int c = cbase + (l & 15);
                const int off = c * 256 +
                    ((ks * 64 + (l >> 4) * 16) ^ ((c & 7) << 4));
                return *(const bf16x8*)(base + off);
            };
            bf16x8 ah0 = frag(xh, wi),      ah1 = frag(xh, wi + 16);
            bf16x8 al0 = frag(xl, wi),      al1 = frag(xl, wi + 16);
            bf16x8 bh0 = frag(xh, wj),      bh1 = frag(xh, wj + 16);
            bf16x8 bl0 = frag(xl, wj),      bl1 = frag(xl, wj + 16);

            acc[0][0] = __builtin_amdgcn_mfma_f32_16x16x32_bf16(ah0, bh0, acc[0][0], 0, 0, 0);
            acc[0][0] = __builtin_amdgcn_mfma_f32_16x16x32_bf16(ah0, bl0, acc[0][0], 0, 0, 0);
            acc[0][0] = __builtin_amdgcn_mfma_f32_16x16x32_bf16(al0, bh0, acc[0][0], 0, 0, 0);

            acc[0][1] = __builtin_amdgcn_mfma_f32_16x16x32_bf16(ah0, bh1, acc[0][1], 0, 0, 0);
            acc[0][1] = __builtin_amdgcn_mfma_f32_16x16x32_bf16(ah0, bl1, acc[0][1], 0, 0, 0);
            acc[0][1] = __builtin_amdgcn_mfma_f32_16x16x32_bf16(al0, bh1, acc[0][1], 0, 0, 0);

            acc[1][0] = __builtin_amdgcn_mfma_f32_16x16x32_bf16(ah1, bh0, acc[1][0], 0, 0, 0);
            acc[1][0] = __builtin_amdgcn_mfma_f32_16x16x32_bf16(ah1, bl0, acc[1][0], 0, 0, 0);
            acc[1][0] = __builtin_amdgcn_mfma_f32_16x16x32_bf16(al1, bh0, acc[1][0], 0, 0, 0);

            acc[1][1] = __builtin_amdgcn_mfma_f32_16x16x32_bf16(ah1, bh1, acc[1][1], 0, 0, 0);
            acc[1][1] = __builtin_amdgcn_mfma_f32_16x16x32_bf16(ah1, bl1, acc[1][1], 0, 0, 0);
            acc[1][1] = __builtin_amdgcn_mfma_f32_16x16x32_bf16(al1, bh1, acc[1][1], 0, 0, 0);
        }
    }
    // ---- epilogue: C/D layout col = lane&15, row = (lane>>4)*4 + reg ----
    #pragma unroll
    for (int a = 0; a < 2; ++a)
        #pragma unroll
        for (int b = 0; b < 2; ++b) {
            const int i0 = wi + a * 16, j0 = wj + b * 16;
            #pragma unroll
            for (int r = 0; r < 4; ++r) {
                const int row = i0 + (l >> 4) * 4 + r;
                const int col = j0 + (l & 15);
                atomicAdd(&M[row * 64 + col], acc[a][b][r]);
            }
        }
}

// ---------------- K2: Beta, w ----------------
__global__ __launch_bounds__(64) void k_beta(const float* __restrict__ M,
                                             const float* __restrict__ Wf,
                                             const float* __restrict__ Wg,
                                             const float* __restrict__ Wh,
                                             const float* __restrict__ Wv,
                                             const float* __restrict__ Gamma,
                                             float* __restrict__ w_out) {
    __shared__ float Tl[64][8];
    __shared__ float STl[64];
    __shared__ float El[64];
    __shared__ float Bl[64];
    __shared__ float ul[8];
    const int t = threadIdx.x;

    float Tr[8] = {};
    for (int b = 0; b < 64; ++b) {
        float m = M[t * 64 + b];
        #pragma unroll
        for (int j = 0; j < 8; ++j) Tr[j] = fmaf(m, Wf[b * 8 + j], Tr[j]);
    }
    #pragma unroll
    for (int j = 0; j < 8; ++j) Tl[t][j] = Tr[j];
    __syncthreads();

    const int i = t >> 3, j = t & 7;
    float st = 0.f;
    for (int a = 0; a < 64; ++a) st = fmaf(Wg[a * 8 + i], Tl[a][j], st);
    STl[t] = st;
    __syncthreads();

    float mx = STl[i * 8];
    #pragma unroll
    for (int jj = 1; jj < 8; ++jj) mx = fmaxf(mx, STl[i * 8 + jj]);
    float e = expf(st - mx);
    El[t] = e;
    __syncthreads();

    float den = 0.f;
    #pragma unroll
    for (int jj = 0; jj < 8; ++jj) den += El[i * 8 + jj];
    Bl[t] = e / den;
    __syncthreads();

    if (t < 8) {
        float u = 0.f;
        #pragma unroll
        for (int ii = 0; ii < 8; ++ii) u += Bl[ii * 8 + t] * Wv[ii];
        ul[t] = u;
    }
    __syncthreads();

    float wv = 0.f;
    #pragma unroll
    for (int jj = 0; jj < 8; ++jj) wv = fmaf(Wh[t * 8 + jj], ul[jj], wv);
    w_out[t] = wv * Gamma[0];
}

// ---------------- K3: fused V + output, 8 groups per block ----------------
// Block handles groups g0..g0+7. V phase: 512 consecutive pixels (128 KB
// contiguous read) -> vbuf[512] in LDS. Out phase: 64 segments, each 8
// consecutive rows = 2 KB contiguous read+write; the V float4 per lane is
// loop-invariant (loaded from LDS once).
__global__ __launch_bounds__(256) void k_vout(const float* __restrict__ x,
                                              const float* __restrict__ wvec,
                                              float* __restrict__ out) {
    __shared__ float vbuf[512];
    __shared__ float wl[64];
    const int t = threadIdx.x;
    if (t < 64) wl[t] = wvec[t];
    __syncthreads();
    const int s = t >> 2, q = t & 3;
    float wreg[16];
    #pragma unroll
    for (int j = 0; j < 16; ++j) wreg[j] = wl[q * 16 + j];

    const int g0 = blockIdx.x * 8;   // grid 1024
    // ---- V phase ----
    #pragma unroll
    for (int it = 0; it < 8; ++it) {
        const int pp = it * 64 + s;
        const float* src = x + ((size_t)g0 * 64 + pp) * 64 + q * 16;
        float part = 0.f;
        #pragma unroll
        for (int jj = 0; jj < 4; ++jj) {
            float4 v = *(const float4*)(src + jj * 4);
            part = fmaf(v.x, wreg[jj * 4 + 0], part);
            part = fmaf(v.y, wreg[jj * 4 + 1], part);
            part = fmaf(v.z, wreg[jj * 4 + 2], part);
            part = fmaf(v.w, wreg[jj * 4 + 3], part);
        }
        part += __shfl_xor(part, 1);
        part += __shfl_xor(part, 2);
        if (q == 0) vbuf[pp] = part;
    }
    __syncthreads();
    // ---- out phase ----
    const float4* x4 = (const float4*)x;
    float4* o4 = (float4*)out;
    const int j = t & 127;           // float4 index within 8-row segment
    const int shalf = t >> 7;        // 0..1 (two segments in flight)
    const float4 vv = ((const float4*)vbuf)[j];
    #pragma unroll 4
    for (int sb = 0; sb < 32; ++sb) {
        const int sseg = sb * 2 + shalf;
        const size_t base = ((size_t)(g0 + 8192 * sseg)) * 16 + j;
        float4 a = x4[base];
        o4[base] = make_float4(a.x + vv.x, a.y + vv.y, a.z + vv.z, a.w + vv.w);
    }
}

extern "C" void kernel_launch(void* const* d_in, const int* in_sizes, int n_in,
                              void* d_out, int out_size, void* d_ws, size_t ws_size,
                              hipStream_t stream) {
    const float* x     = (const float*)d_in[0];
    const float* Wf    = (const float*)d_in[1];
    const float* Wg    = (const float*)d_in[2];
    const float* Wh    = (const float*)d_in[3];
    const float* Wv    = (const float*)d_in[4];
    const float* Gamma = (const float*)d_in[5];
    float* out = (float*)d_out;

    float* M = (float*)d_ws;          // 4096 floats
    float* w = M + 4096;              // 64 floats

    hipMemsetAsync(M, 0, 4096 * sizeof(float), stream);
    hipLaunchKernelGGL(k_cov, dim3(COV_BLOCKS), dim3(256), 0, stream, x, M);
    hipLaunchKernelGGL(k_beta, dim3(1), dim3(64), 0, stream, M, Wf, Wg, Wh, Wv, Gamma, w);
    hipLaunchKernelGGL(k_vout, dim3(1024), dim3(256), 0, stream, x, w, out);
}